// Round 1
// baseline (3265.294 us; speedup 1.0000x reference)
//
#include <hip/hip_runtime.h>

#define NNODES 100000
#define IN_CH 128
#define HID 64

// ---------------- degree / norm ----------------
__global__ void k_deg_init(float* __restrict__ deg, int n) {
    int i = blockIdx.x * blockDim.x + threadIdx.x;
    if (i < n) deg[i] = 1.0f;  // self-loop
}

__global__ void k_deg_count(const int* __restrict__ dst, float* __restrict__ deg, int E) {
    int e = blockIdx.x * blockDim.x + threadIdx.x;
    if (e < E) atomicAdd(&deg[dst[e]], 1.0f);
}

__global__ void k_rsqrt_inplace(float* __restrict__ deg, int n) {
    int i = blockIdx.x * blockDim.x + threadIdx.x;
    if (i < n) deg[i] = rsqrtf(deg[i]);  // deg >= 1 always (self-loop)
}

// ---------------- layer 1: hp1 = dinv * (x @ W1) ----------------
// 16 nodes per 256-thread block. W1 (128x64, 32KB) + 16 x-rows (8KB) in LDS.
// thread k = tid&63 computes output dim k for nodes n0, n0+4, n0+8, n0+12.
__global__ __launch_bounds__(256) void k_gemm1(const float* __restrict__ x,
                                               const float* __restrict__ W1,
                                               const float* __restrict__ dinv,
                                               float* __restrict__ hp1) {
    __shared__ float sW[IN_CH * HID];   // 32 KB
    __shared__ float sx[16 * IN_CH];    // 8 KB
    const int tid = threadIdx.x;
    const int node0 = blockIdx.x * 16;  // N % 16 == 0 for N=100000

    {
        const float4* g = (const float4*)W1;
        float4* s = (float4*)sW;
        for (int i = tid; i < IN_CH * HID / 4; i += 256) s[i] = g[i];
    }
    {
        const float4* g = (const float4*)(x + (size_t)node0 * IN_CH);
        float4* s = (float4*)sx;
        for (int i = tid; i < 16 * IN_CH / 4; i += 256) s[i] = g[i];
    }
    __syncthreads();

    const int k  = tid & 63;
    const int n0 = tid >> 6;  // 0..3 (uniform within a wave -> sx reads broadcast)
    float a0 = 0.f, a1 = 0.f, a2 = 0.f, a3 = 0.f;
#pragma unroll 8
    for (int j = 0; j < IN_CH; ++j) {
        float w = sW[j * HID + k];
        a0 = fmaf(sx[(n0     ) * IN_CH + j], w, a0);
        a1 = fmaf(sx[(n0 +  4) * IN_CH + j], w, a1);
        a2 = fmaf(sx[(n0 +  8) * IN_CH + j], w, a2);
        a3 = fmaf(sx[(n0 + 12) * IN_CH + j], w, a3);
    }
    hp1[(size_t)(node0 + n0     ) * HID + k] = a0 * dinv[node0 + n0];
    hp1[(size_t)(node0 + n0 +  4) * HID + k] = a1 * dinv[node0 + n0 + 4];
    hp1[(size_t)(node0 + n0 +  8) * HID + k] = a2 * dinv[node0 + n0 + 8];
    hp1[(size_t)(node0 + n0 + 12) * HID + k] = a3 * dinv[node0 + n0 + 12];
}

// ---------------- layer 1 scatter: acc1[d] += hp1[s] ----------------
// 16 threads per edge, each handles 4 consecutive dims (float4 gather + 4 atomics).
__global__ __launch_bounds__(256) void k_scatter1(const int* __restrict__ src,
                                                  const int* __restrict__ dst,
                                                  const float* __restrict__ hp1,
                                                  float* __restrict__ acc, int E) {
    int gid = blockIdx.x * blockDim.x + threadIdx.x;
    int e = gid >> 4;
    if (e >= E) return;
    int l = gid & 15;
    int s = src[e], d = dst[e];
    float4 v = *(const float4*)(hp1 + (size_t)s * HID + l * 4);
    float* a = acc + (size_t)d * HID + l * 4;
    atomicAdd(a + 0, v.x);
    atomicAdd(a + 1, v.y);
    atomicAdd(a + 2, v.z);
    atomicAdd(a + 3, v.w);
}

// ---------------- layer 2 projection (fused relu/bias/norm of layer-1 output) ----
// One wave per node: h[k] = relu(dinv*(acc1+hp1) + b1[k]); hp2[c] = dinv * sum_k h[k]*W2[k][c]
__global__ __launch_bounds__(256) void k_gemm2(const float* __restrict__ hp1,
                                               const float* __restrict__ acc1,
                                               const float* __restrict__ dinv,
                                               const float* __restrict__ b1,
                                               const float* __restrict__ W2,
                                               float* __restrict__ hp2, int N) {
    int wave = (blockIdx.x * blockDim.x + threadIdx.x) >> 6;
    int k = threadIdx.x & 63;
    if (wave >= N) return;
    float dj = dinv[wave];
    size_t base = (size_t)wave * HID + k;
    float h = fmaxf(fmaf(dj, acc1[base] + hp1[base], b1[k]), 0.0f);
    float p0 = h * W2[k * 2 + 0];
    float p1 = h * W2[k * 2 + 1];
#pragma unroll
    for (int off = 32; off; off >>= 1) {
        p0 += __shfl_xor(p0, off);
        p1 += __shfl_xor(p1, off);
    }
    if (k == 0) {
        hp2[(size_t)wave * 2 + 0] = p0 * dj;
        hp2[(size_t)wave * 2 + 1] = p1 * dj;
    }
}

// ---------------- layer 2 scatter: acc2[d] += hp2[s] (2 dims) ----------------
__global__ void k_scatter2(const int* __restrict__ src, const int* __restrict__ dst,
                           const float* __restrict__ hp2, float* __restrict__ acc2, int E) {
    int e = blockIdx.x * blockDim.x + threadIdx.x;
    if (e >= E) return;
    int s = src[e], d = dst[e];
    float2 v = *(const float2*)(hp2 + (size_t)s * 2);
    atomicAdd(&acc2[(size_t)d * 2 + 0], v.x);
    atomicAdd(&acc2[(size_t)d * 2 + 1], v.y);
}

// ---------------- epilogue: out = dinv*(acc2 + hp2) + b2 ----------------
__global__ void k_finish2(const float* __restrict__ hp2, const float* __restrict__ acc2,
                          const float* __restrict__ dinv, const float* __restrict__ b2,
                          float* __restrict__ out, int N) {
    int i = blockIdx.x * blockDim.x + threadIdx.x;
    if (i >= 2 * N) return;
    int j = i >> 1, c = i & 1;
    out[i] = fmaf(dinv[j], acc2[i] + hp2[i], b2[c]);
}

extern "C" void kernel_launch(void* const* d_in, const int* in_sizes, int n_in,
                              void* d_out, int out_size, void* d_ws, size_t ws_size,
                              hipStream_t stream) {
    const float* x  = (const float*)d_in[0];
    const int*   ei = (const int*)d_in[1];   // harness converts integer inputs to int32
    const float* W1 = (const float*)d_in[2];
    const float* b1 = (const float*)d_in[3];
    const float* W2 = (const float*)d_in[4];
    const float* b2 = (const float*)d_in[5];
    float* out = (float*)d_out;

    const int N = NNODES;
    const int E = in_sizes[1] / 2;
    const int* src = ei;
    const int* dst = ei + E;

    // workspace carve-up (256B aligned)
    char* ws = (char*)d_ws;
    size_t o = 0;
    auto carve = [&](size_t bytes) -> char* {
        char* p = ws + o;
        o = (o + bytes + 255) & ~(size_t)255;
        return p;
    };
    float* dinv = (float*)carve((size_t)N * 4);            // deg -> dinv in place
    float* hp1  = (float*)carve((size_t)N * HID * 4);      // 25.6 MB
    float* acc1 = (float*)carve((size_t)N * HID * 4);      // 25.6 MB
    float* hp2  = (float*)carve((size_t)N * 2 * 4);
    float* acc2 = (float*)carve((size_t)N * 2 * 4);
    (void)ws_size;

    // degree + rsqrt
    k_deg_init<<<(N + 255) / 256, 256, 0, stream>>>(dinv, N);
    k_deg_count<<<(E + 255) / 256, 256, 0, stream>>>(dst, dinv, E);
    k_rsqrt_inplace<<<(N + 255) / 256, 256, 0, stream>>>(dinv, N);

    // layer 1
    k_gemm1<<<N / 16, 256, 0, stream>>>(x, W1, dinv, hp1);
    hipMemsetAsync(acc1, 0, (size_t)N * HID * 4, stream);
    {
        long long total = (long long)E * 16;
        k_scatter1<<<(unsigned)((total + 255) / 256), 256, 0, stream>>>(src, dst, hp1, acc1, E);
    }

    // layer 2 projection (fused relu) + scatter + epilogue
    k_gemm2<<<(unsigned)(((size_t)N * 64 + 255) / 256), 256, 0, stream>>>(hp1, acc1, dinv, b1, W2, hp2, N);
    hipMemsetAsync(acc2, 0, (size_t)N * 2 * 4, stream);
    k_scatter2<<<(E + 255) / 256, 256, 0, stream>>>(src, dst, hp2, acc2, E);
    k_finish2<<<(2 * N + 255) / 256, 256, 0, stream>>>(hp2, acc2, dinv, b2, out, N);
}

// Round 2
// 1042.166 us; speedup vs baseline: 3.1332x; 3.1332x over previous
//
#include <hip/hip_runtime.h>

#define IN_CH 128
#define HID 64

// ---------------- phase A: histogram of dst (= in-degree) ----------------
__global__ void k_hist(const int* __restrict__ dst, int* __restrict__ cnt, int E) {
    int e = blockIdx.x * blockDim.x + threadIdx.x;
    if (e < E) atomicAdd(&cnt[dst[e]], 1);
}

// ---------------- phase B: single-block scan -> rowptr/cursor/dinv ----------------
__global__ __launch_bounds__(1024) void k_scan(const int* __restrict__ cnt,
                                               int* __restrict__ rowptr,
                                               int* __restrict__ cursor,
                                               float* __restrict__ dinv, int N) {
    __shared__ int ssum[1024];
    const int t = threadIdx.x;
    const int C = (N + 1023) / 1024;
    int lo = t * C;
    int hi = min(N, lo + C);
    int s = 0;
    for (int i = lo; i < hi; ++i) s += cnt[i];
    ssum[t] = s;
    __syncthreads();
    for (int off = 1; off < 1024; off <<= 1) {        // inclusive Hillis-Steele
        int v = (t >= off) ? ssum[t - off] : 0;
        __syncthreads();
        ssum[t] += v;
        __syncthreads();
    }
    int run = (t == 0) ? 0 : ssum[t - 1];
    for (int i = lo; i < hi; ++i) {
        int c = cnt[i];
        rowptr[i] = run;
        cursor[i] = run;
        dinv[i] = rsqrtf(1.0f + (float)c);            // +1 self-loop
        run += c;
    }
    if (t == 1023) rowptr[N] = run;                   // == E
}

// ---------------- phase C: bucket src ids by dst ----------------
__global__ void k_bucket(const int* __restrict__ src, const int* __restrict__ dst,
                         int* __restrict__ cursor, int* __restrict__ esorted, int E) {
    int e = blockIdx.x * blockDim.x + threadIdx.x;
    if (e >= E) return;
    int pos = atomicAdd(&cursor[dst[e]], 1);
    esorted[pos] = src[e];
}

// ---------------- layer 1 GEMM: hp1 = dinv * (x @ W1) ----------------
// 16 nodes per 256-thread block; W1 (32KB) + 16 x-rows (8KB) in LDS.
__global__ __launch_bounds__(256) void k_gemm1(const float* __restrict__ x,
                                               const float* __restrict__ W1,
                                               const float* __restrict__ dinv,
                                               float* __restrict__ hp1, int N) {
    __shared__ float sW[IN_CH * HID];
    __shared__ float sx[16 * IN_CH];
    const int tid = threadIdx.x;
    const int node0 = blockIdx.x * 16;

    {
        const float4* g = (const float4*)W1;
        float4* s = (float4*)sW;
        for (int i = tid; i < IN_CH * HID / 4; i += 256) s[i] = g[i];
    }
    {
        const float4* g = (const float4*)(x + (size_t)node0 * IN_CH);
        float4* s = (float4*)sx;
        for (int i = tid; i < 16 * IN_CH / 4; i += 256) s[i] = g[i];
    }
    __syncthreads();

    const int k  = tid & 63;
    const int n0 = tid >> 6;  // 0..3
    float a0 = 0.f, a1 = 0.f, a2 = 0.f, a3 = 0.f;
#pragma unroll 8
    for (int j = 0; j < IN_CH; ++j) {
        float w = sW[j * HID + k];
        a0 = fmaf(sx[(n0     ) * IN_CH + j], w, a0);
        a1 = fmaf(sx[(n0 +  4) * IN_CH + j], w, a1);
        a2 = fmaf(sx[(n0 +  8) * IN_CH + j], w, a2);
        a3 = fmaf(sx[(n0 + 12) * IN_CH + j], w, a3);
    }
    hp1[(size_t)(node0 + n0     ) * HID + k] = a0 * dinv[node0 + n0];
    hp1[(size_t)(node0 + n0 +  4) * HID + k] = a1 * dinv[node0 + n0 + 4];
    hp1[(size_t)(node0 + n0 +  8) * HID + k] = a2 * dinv[node0 + n0 + 8];
    hp1[(size_t)(node0 + n0 + 12) * HID + k] = a3 * dinv[node0 + n0 + 12];
}

// ---- layer 1 aggregate + relu + bias + layer 2 projection, fused ----
// One 64-lane wave per node; lane k owns hidden dim k. Gather of hp1 rows is
// fully coalesced (64 lanes x 4B = one 256B row per edge). No atomics.
__global__ __launch_bounds__(256) void k_agg1(const int* __restrict__ rowptr,
                                              const int* __restrict__ esorted,
                                              const float* __restrict__ hp1,
                                              const float* __restrict__ dinv,
                                              const float* __restrict__ b1,
                                              const float* __restrict__ W2,
                                              float* __restrict__ hp2, int N) {
    int wid = (blockIdx.x * blockDim.x + threadIdx.x) >> 6;
    if (wid >= N) return;
    int k = threadIdx.x & 63;
    int beg = rowptr[wid], end = rowptr[wid + 1];
    float acc = hp1[(size_t)wid * HID + k];           // self-loop term
    for (int e = beg; e < end; ++e) {
        int s = esorted[e];
        acc += hp1[(size_t)s * HID + k];
    }
    float dj = dinv[wid];
    float h = fmaxf(fmaf(dj, acc, b1[k]), 0.0f);      // layer-1 output + relu
    float p0 = h * W2[k * 2 + 0];
    float p1 = h * W2[k * 2 + 1];
#pragma unroll
    for (int off = 32; off; off >>= 1) {
        p0 += __shfl_xor(p0, off);
        p1 += __shfl_xor(p1, off);
    }
    if (k == 0) {
        hp2[(size_t)wid * 2 + 0] = p0 * dj;
        hp2[(size_t)wid * 2 + 1] = p1 * dj;
    }
}

// ---------------- layer 2 aggregate + epilogue ----------------
__global__ void k_agg2(const int* __restrict__ rowptr, const int* __restrict__ esorted,
                       const float* __restrict__ hp2, const float* __restrict__ dinv,
                       const float* __restrict__ b2, float* __restrict__ out, int N) {
    int j = blockIdx.x * blockDim.x + threadIdx.x;
    if (j >= N) return;
    int beg = rowptr[j], end = rowptr[j + 1];
    float2 a = *(const float2*)(hp2 + (size_t)j * 2);  // self-loop term
    for (int e = beg; e < end; ++e) {
        int s = esorted[e];
        float2 v = *(const float2*)(hp2 + (size_t)s * 2);
        a.x += v.x;
        a.y += v.y;
    }
    float dj = dinv[j];
    out[(size_t)j * 2 + 0] = fmaf(dj, a.x, b2[0]);
    out[(size_t)j * 2 + 1] = fmaf(dj, a.y, b2[1]);
}

extern "C" void kernel_launch(void* const* d_in, const int* in_sizes, int n_in,
                              void* d_out, int out_size, void* d_ws, size_t ws_size,
                              hipStream_t stream) {
    const float* x  = (const float*)d_in[0];
    const int*   ei = (const int*)d_in[1];
    const float* W1 = (const float*)d_in[2];
    const float* b1 = (const float*)d_in[3];
    const float* W2 = (const float*)d_in[4];
    const float* b2 = (const float*)d_in[5];
    float* out = (float*)d_out;

    const int N = in_sizes[0] / IN_CH;   // 100000
    const int E = in_sizes[1] / 2;       // 3200000
    const int* src = ei;
    const int* dst = ei + E;

    char* ws = (char*)d_ws;
    size_t o = 0;
    auto carve = [&](size_t bytes) -> char* {
        char* p = ws + o;
        o = (o + bytes + 255) & ~(size_t)255;
        return p;
    };
    int*   cnt     = (int*)carve((size_t)N * 4);
    int*   rowptr  = (int*)carve(((size_t)N + 1) * 4);
    int*   cursor  = (int*)carve((size_t)N * 4);
    float* dinv    = (float*)carve((size_t)N * 4);
    int*   esorted = (int*)carve((size_t)E * 4);          // 12.8 MB
    float* hp1     = (float*)carve((size_t)N * HID * 4);  // 25.6 MB
    float* hp2     = (float*)carve((size_t)N * 2 * 4);
    (void)ws_size;

    hipMemsetAsync(cnt, 0, (size_t)N * 4, stream);
    k_hist<<<(E + 255) / 256, 256, 0, stream>>>(dst, cnt, E);
    k_scan<<<1, 1024, 0, stream>>>(cnt, rowptr, cursor, dinv, N);
    k_bucket<<<(E + 255) / 256, 256, 0, stream>>>(src, dst, cursor, esorted, E);

    k_gemm1<<<(N + 15) / 16, 256, 0, stream>>>(x, W1, dinv, hp1, N);
    k_agg1<<<(unsigned)(((size_t)N * 64 + 255) / 256), 256, 0, stream>>>(
        rowptr, esorted, hp1, dinv, b1, W2, hp2, N);
    k_agg2<<<(N + 255) / 256, 256, 0, stream>>>(rowptr, esorted, hp2, dinv, b2, out, N);
}

// Round 3
// 786.891 us; speedup vs baseline: 4.1496x; 1.3244x over previous
//
#include <hip/hip_runtime.h>

#define IN_CH 128
#define HID 64
#define SCAN_CHUNK 1024  // elements per scan block (256 threads x int4)

// ---------------- phase A: histogram of dst (= in-degree) ----------------
__global__ void k_hist(const int* __restrict__ dst, int* __restrict__ cnt, int E) {
    int e = blockIdx.x * blockDim.x + threadIdx.x;
    if (e < E) atomicAdd(&cnt[dst[e]], 1);
}

// ---------------- phase B: multi-block exclusive scan ----------------
// B1: per-chunk sums (coalesced int4 loads, shuffle+LDS reduce)
__global__ __launch_bounds__(256) void k_scan_blocksum(const int* __restrict__ cnt,
                                                       int* __restrict__ bsum, int N) {
    int t = threadIdx.x;
    int base = blockIdx.x * SCAN_CHUNK + t * 4;
    int4 v = make_int4(0, 0, 0, 0);
    if (base + 3 < N) v = *(const int4*)(cnt + base);
    else {
        if (base     < N) v.x = cnt[base];
        if (base + 1 < N) v.y = cnt[base + 1];
        if (base + 2 < N) v.z = cnt[base + 2];
        if (base + 3 < N) v.w = cnt[base + 3];
    }
    int s = v.x + v.y + v.z + v.w;
#pragma unroll
    for (int off = 32; off; off >>= 1) s += __shfl_down(s, off);
    __shared__ int ws[4];
    if ((t & 63) == 0) ws[t >> 6] = s;
    __syncthreads();
    if (t == 0) bsum[blockIdx.x] = ws[0] + ws[1] + ws[2] + ws[3];
}

// B2: exclusive scan of the (<=128) block sums, in place
__global__ __launch_bounds__(128) void k_scan_bsums(int* __restrict__ bsum, int nb) {
    __shared__ int sh[128];
    int t = threadIdx.x;
    int v = (t < nb) ? bsum[t] : 0;
    sh[t] = v;
    __syncthreads();
    for (int off = 1; off < 128; off <<= 1) {
        int u = (t >= off) ? sh[t - off] : 0;
        __syncthreads();
        sh[t] += u;
        __syncthreads();
    }
    if (t < nb) bsum[t] = (t == 0) ? 0 : sh[t - 1];
}

// B3: per-chunk exclusive scan + apply -> rowptr/cursor/dinv
__global__ __launch_bounds__(256) void k_scan_apply(const int* __restrict__ cnt,
                                                    const int* __restrict__ boff,
                                                    int* __restrict__ rowptr,
                                                    int* __restrict__ cursor,
                                                    float* __restrict__ dinv,
                                                    int N, int E) {
    int t = threadIdx.x;
    int base = blockIdx.x * SCAN_CHUNK + t * 4;
    int4 v = make_int4(0, 0, 0, 0);
    if (base + 3 < N) v = *(const int4*)(cnt + base);
    else {
        if (base     < N) v.x = cnt[base];
        if (base + 1 < N) v.y = cnt[base + 1];
        if (base + 2 < N) v.z = cnt[base + 2];
        if (base + 3 < N) v.w = cnt[base + 3];
    }
    int tsum = v.x + v.y + v.z + v.w;
    __shared__ int sh[256];
    sh[t] = tsum;
    __syncthreads();
    for (int off = 1; off < 256; off <<= 1) {
        int u = (t >= off) ? sh[t - off] : 0;
        __syncthreads();
        sh[t] += u;
        __syncthreads();
    }
    int run = ((t == 0) ? 0 : sh[t - 1]) + boff[blockIdx.x];
    int p0 = run;
    int p1 = p0 + v.x;
    int p2 = p1 + v.y;
    int p3 = p2 + v.z;
    if (base < N) {
        rowptr[base] = p0; cursor[base] = p0; dinv[base] = rsqrtf(1.0f + (float)v.x);
    }
    if (base + 1 < N) {
        rowptr[base + 1] = p1; cursor[base + 1] = p1; dinv[base + 1] = rsqrtf(1.0f + (float)v.y);
    }
    if (base + 2 < N) {
        rowptr[base + 2] = p2; cursor[base + 2] = p2; dinv[base + 2] = rsqrtf(1.0f + (float)v.z);
    }
    if (base + 3 < N) {
        rowptr[base + 3] = p3; cursor[base + 3] = p3; dinv[base + 3] = rsqrtf(1.0f + (float)v.w);
    }
    if (blockIdx.x == 0 && t == 0) rowptr[N] = E;
}

// ---------------- phase C: bucket src ids by dst ----------------
__global__ void k_bucket(const int* __restrict__ src, const int* __restrict__ dst,
                         int* __restrict__ cursor, int* __restrict__ esorted, int E) {
    int e = blockIdx.x * blockDim.x + threadIdx.x;
    if (e >= E) return;
    int pos = atomicAdd(&cursor[dst[e]], 1);
    esorted[pos] = src[e];
}

// ---------------- layer 1 GEMM: hp1 = dinv * (x @ W1) ----------------
__global__ __launch_bounds__(256) void k_gemm1(const float* __restrict__ x,
                                               const float* __restrict__ W1,
                                               const float* __restrict__ dinv,
                                               float* __restrict__ hp1, int N) {
    __shared__ float sW[IN_CH * HID];
    __shared__ float sx[16 * IN_CH];
    const int tid = threadIdx.x;
    const int node0 = blockIdx.x * 16;

    {
        const float4* g = (const float4*)W1;
        float4* s = (float4*)sW;
        for (int i = tid; i < IN_CH * HID / 4; i += 256) s[i] = g[i];
    }
    {
        const float4* g = (const float4*)(x + (size_t)node0 * IN_CH);
        float4* s = (float4*)sx;
        for (int i = tid; i < 16 * IN_CH / 4; i += 256) s[i] = g[i];
    }
    __syncthreads();

    const int k  = tid & 63;
    const int n0 = tid >> 6;  // 0..3
    float a0 = 0.f, a1 = 0.f, a2 = 0.f, a3 = 0.f;
#pragma unroll 8
    for (int j = 0; j < IN_CH; ++j) {
        float w = sW[j * HID + k];
        a0 = fmaf(sx[(n0     ) * IN_CH + j], w, a0);
        a1 = fmaf(sx[(n0 +  4) * IN_CH + j], w, a1);
        a2 = fmaf(sx[(n0 +  8) * IN_CH + j], w, a2);
        a3 = fmaf(sx[(n0 + 12) * IN_CH + j], w, a3);
    }
    hp1[(size_t)(node0 + n0     ) * HID + k] = a0 * dinv[node0 + n0];
    hp1[(size_t)(node0 + n0 +  4) * HID + k] = a1 * dinv[node0 + n0 + 4];
    hp1[(size_t)(node0 + n0 +  8) * HID + k] = a2 * dinv[node0 + n0 + 8];
    hp1[(size_t)(node0 + n0 + 12) * HID + k] = a3 * dinv[node0 + n0 + 12];
}

// ---- layer 1 aggregate + relu + bias + layer 2 projection, fused ----
__global__ __launch_bounds__(256) void k_agg1(const int* __restrict__ rowptr,
                                              const int* __restrict__ esorted,
                                              const float* __restrict__ hp1,
                                              const float* __restrict__ dinv,
                                              const float* __restrict__ b1,
                                              const float* __restrict__ W2,
                                              float* __restrict__ hp2, int N) {
    int wid = (blockIdx.x * blockDim.x + threadIdx.x) >> 6;
    if (wid >= N) return;
    int k = threadIdx.x & 63;
    int beg = rowptr[wid], end = rowptr[wid + 1];
    float acc = hp1[(size_t)wid * HID + k];           // self-loop term
    for (int e = beg; e < end; ++e) {
        int s = esorted[e];
        acc += hp1[(size_t)s * HID + k];
    }
    float dj = dinv[wid];
    float h = fmaxf(fmaf(dj, acc, b1[k]), 0.0f);
    float p0 = h * W2[k * 2 + 0];
    float p1 = h * W2[k * 2 + 1];
#pragma unroll
    for (int off = 32; off; off >>= 1) {
        p0 += __shfl_xor(p0, off);
        p1 += __shfl_xor(p1, off);
    }
    if (k == 0) {
        hp2[(size_t)wid * 2 + 0] = p0 * dj;
        hp2[(size_t)wid * 2 + 1] = p1 * dj;
    }
}

// ---------------- layer 2 aggregate + epilogue ----------------
__global__ void k_agg2(const int* __restrict__ rowptr, const int* __restrict__ esorted,
                       const float* __restrict__ hp2, const float* __restrict__ dinv,
                       const float* __restrict__ b2, float* __restrict__ out, int N) {
    int j = blockIdx.x * blockDim.x + threadIdx.x;
    if (j >= N) return;
    int beg = rowptr[j], end = rowptr[j + 1];
    float2 a = *(const float2*)(hp2 + (size_t)j * 2);
    for (int e = beg; e < end; ++e) {
        int s = esorted[e];
        float2 v = *(const float2*)(hp2 + (size_t)s * 2);
        a.x += v.x;
        a.y += v.y;
    }
    float dj = dinv[j];
    out[(size_t)j * 2 + 0] = fmaf(dj, a.x, b2[0]);
    out[(size_t)j * 2 + 1] = fmaf(dj, a.y, b2[1]);
}

extern "C" void kernel_launch(void* const* d_in, const int* in_sizes, int n_in,
                              void* d_out, int out_size, void* d_ws, size_t ws_size,
                              hipStream_t stream) {
    const float* x  = (const float*)d_in[0];
    const int*   ei = (const int*)d_in[1];
    const float* W1 = (const float*)d_in[2];
    const float* b1 = (const float*)d_in[3];
    const float* W2 = (const float*)d_in[4];
    const float* b2 = (const float*)d_in[5];
    float* out = (float*)d_out;

    const int N = in_sizes[0] / IN_CH;   // 100000
    const int E = in_sizes[1] / 2;       // 3200000
    const int* src = ei;
    const int* dst = ei + E;
    const int NB = (N + SCAN_CHUNK - 1) / SCAN_CHUNK;  // 98 (<=128 required)

    char* ws = (char*)d_ws;
    size_t o = 0;
    auto carve = [&](size_t bytes) -> char* {
        char* p = ws + o;
        o = (o + bytes + 255) & ~(size_t)255;
        return p;
    };
    int*   cnt     = (int*)carve((size_t)N * 4);
    int*   rowptr  = (int*)carve(((size_t)N + 1) * 4);
    int*   cursor  = (int*)carve((size_t)N * 4);
    float* dinv    = (float*)carve((size_t)N * 4);
    int*   bsum    = (int*)carve(128 * 4);
    int*   esorted = (int*)carve((size_t)E * 4);          // 12.8 MB
    float* hp1     = (float*)carve((size_t)N * HID * 4);  // 25.6 MB
    float* hp2     = (float*)carve((size_t)N * 2 * 4);
    (void)ws_size;

    hipMemsetAsync(cnt, 0, (size_t)N * 4, stream);
    k_hist<<<(E + 255) / 256, 256, 0, stream>>>(dst, cnt, E);
    k_scan_blocksum<<<NB, 256, 0, stream>>>(cnt, bsum, N);
    k_scan_bsums<<<1, 128, 0, stream>>>(bsum, NB);
    k_scan_apply<<<NB, 256, 0, stream>>>(cnt, bsum, rowptr, cursor, dinv, N, E);
    k_bucket<<<(E + 255) / 256, 256, 0, stream>>>(src, dst, cursor, esorted, E);

    k_gemm1<<<(N + 15) / 16, 256, 0, stream>>>(x, W1, dinv, hp1, N);
    k_agg1<<<(unsigned)(((size_t)N * 64 + 255) / 256), 256, 0, stream>>>(
        rowptr, esorted, hp1, dinv, b1, W2, hp2, N);
    k_agg2<<<(N + 255) / 256, 256, 0, stream>>>(rowptr, esorted, hp2, dinv, b2, out, N);
}

// Round 4
// 634.715 us; speedup vs baseline: 5.1445x; 1.2398x over previous
//
#include <hip/hip_runtime.h>

#define IN_CH 128
#define HID 64
#define SCAN_CHUNK 1024  // elements per scan block (256 threads x int4)

// ---------------- phase A: histogram of dst (= in-degree) ----------------
__global__ void k_hist(const int* __restrict__ dst, int* __restrict__ cnt, int E) {
    int e = blockIdx.x * blockDim.x + threadIdx.x;
    if (e < E) atomicAdd(&cnt[dst[e]], 1);
}

// ---------------- phase B: multi-block exclusive scan ----------------
__global__ __launch_bounds__(256) void k_scan_blocksum(const int* __restrict__ cnt,
                                                       int* __restrict__ bsum, int N) {
    int t = threadIdx.x;
    int base = blockIdx.x * SCAN_CHUNK + t * 4;
    int4 v = make_int4(0, 0, 0, 0);
    if (base + 3 < N) v = *(const int4*)(cnt + base);
    else {
        if (base     < N) v.x = cnt[base];
        if (base + 1 < N) v.y = cnt[base + 1];
        if (base + 2 < N) v.z = cnt[base + 2];
        if (base + 3 < N) v.w = cnt[base + 3];
    }
    int s = v.x + v.y + v.z + v.w;
#pragma unroll
    for (int off = 32; off; off >>= 1) s += __shfl_down(s, off);
    __shared__ int ws[4];
    if ((t & 63) == 0) ws[t >> 6] = s;
    __syncthreads();
    if (t == 0) bsum[blockIdx.x] = ws[0] + ws[1] + ws[2] + ws[3];
}

__global__ __launch_bounds__(128) void k_scan_bsums(int* __restrict__ bsum, int nb) {
    __shared__ int sh[128];
    int t = threadIdx.x;
    int v = (t < nb) ? bsum[t] : 0;
    sh[t] = v;
    __syncthreads();
    for (int off = 1; off < 128; off <<= 1) {
        int u = (t >= off) ? sh[t - off] : 0;
        __syncthreads();
        sh[t] += u;
        __syncthreads();
    }
    if (t < nb) bsum[t] = (t == 0) ? 0 : sh[t - 1];
}

__global__ __launch_bounds__(256) void k_scan_apply(const int* __restrict__ cnt,
                                                    const int* __restrict__ boff,
                                                    int* __restrict__ rowptr,
                                                    int* __restrict__ cursor,
                                                    float* __restrict__ dinv,
                                                    int N, int E) {
    int t = threadIdx.x;
    int base = blockIdx.x * SCAN_CHUNK + t * 4;
    int4 v = make_int4(0, 0, 0, 0);
    if (base + 3 < N) v = *(const int4*)(cnt + base);
    else {
        if (base     < N) v.x = cnt[base];
        if (base + 1 < N) v.y = cnt[base + 1];
        if (base + 2 < N) v.z = cnt[base + 2];
        if (base + 3 < N) v.w = cnt[base + 3];
    }
    int tsum = v.x + v.y + v.z + v.w;
    __shared__ int sh[256];
    sh[t] = tsum;
    __syncthreads();
    for (int off = 1; off < 256; off <<= 1) {
        int u = (t >= off) ? sh[t - off] : 0;
        __syncthreads();
        sh[t] += u;
        __syncthreads();
    }
    int run = ((t == 0) ? 0 : sh[t - 1]) + boff[blockIdx.x];
    int p0 = run;
    int p1 = p0 + v.x;
    int p2 = p1 + v.y;
    int p3 = p2 + v.z;
    if (base < N) {
        rowptr[base] = p0; cursor[base] = p0; dinv[base] = rsqrtf(1.0f + (float)v.x);
    }
    if (base + 1 < N) {
        rowptr[base + 1] = p1; cursor[base + 1] = p1; dinv[base + 1] = rsqrtf(1.0f + (float)v.y);
    }
    if (base + 2 < N) {
        rowptr[base + 2] = p2; cursor[base + 2] = p2; dinv[base + 2] = rsqrtf(1.0f + (float)v.z);
    }
    if (base + 3 < N) {
        rowptr[base + 3] = p3; cursor[base + 3] = p3; dinv[base + 3] = rsqrtf(1.0f + (float)v.w);
    }
    if (blockIdx.x == 0 && t == 0) rowptr[N] = E;
}

// ---------------- phase C: bucket src ids by dst, XCD-partitioned ----------------
// Neighboring dst nodes are adjacent in esorted; partition by dst>>7 (128-node
// groups, interleaved mod 8) so each esorted cache line is written by blocks of
// ONE group (one XCD under round-robin blockIdx->XCD). Writes then accumulate
// to full lines in that XCD's L2 instead of 8 partial-line writebacks.
// Edge list is read 8x via nontemporal loads (L3-served, no L2 pollution).
__global__ __launch_bounds__(256) void k_bucket(const int* __restrict__ src,
                                                const int* __restrict__ dst,
                                                int* __restrict__ cursor,
                                                int* __restrict__ esorted, int E) {
    const int grp    = blockIdx.x & 7;   // heuristic XCD id (round-robin dispatch)
    const int blk    = blockIdx.x >> 3;
    const int stride = (gridDim.x >> 3) * 256;
    for (int e = blk * 256 + threadIdx.x; e < E; e += stride) {
        int d = __builtin_nontemporal_load(dst + e);
        if (((d >> 7) & 7) == grp) {
            int s = __builtin_nontemporal_load(src + e);
            int pos = atomicAdd(&cursor[d], 1);
            esorted[pos] = s;
        }
    }
}

// ---------------- layer 1 GEMM: hp1 = dinv * (x @ W1) ----------------
__global__ __launch_bounds__(256) void k_gemm1(const float* __restrict__ x,
                                               const float* __restrict__ W1,
                                               const float* __restrict__ dinv,
                                               float* __restrict__ hp1, int N) {
    __shared__ float sW[IN_CH * HID];
    __shared__ float sx[16 * IN_CH];
    const int tid = threadIdx.x;
    const int node0 = blockIdx.x * 16;

    {
        const float4* g = (const float4*)W1;
        float4* s = (float4*)sW;
        for (int i = tid; i < IN_CH * HID / 4; i += 256) s[i] = g[i];
    }
    {
        const float4* g = (const float4*)(x + (size_t)node0 * IN_CH);
        float4* s = (float4*)sx;
        for (int i = tid; i < 16 * IN_CH / 4; i += 256) s[i] = g[i];
    }
    __syncthreads();

    const int k  = tid & 63;
    const int n0 = tid >> 6;  // 0..3
    float a0 = 0.f, a1 = 0.f, a2 = 0.f, a3 = 0.f;
#pragma unroll 8
    for (int j = 0; j < IN_CH; ++j) {
        float w = sW[j * HID + k];
        a0 = fmaf(sx[(n0     ) * IN_CH + j], w, a0);
        a1 = fmaf(sx[(n0 +  4) * IN_CH + j], w, a1);
        a2 = fmaf(sx[(n0 +  8) * IN_CH + j], w, a2);
        a3 = fmaf(sx[(n0 + 12) * IN_CH + j], w, a3);
    }
    hp1[(size_t)(node0 + n0     ) * HID + k] = a0 * dinv[node0 + n0];
    hp1[(size_t)(node0 + n0 +  4) * HID + k] = a1 * dinv[node0 + n0 + 4];
    hp1[(size_t)(node0 + n0 +  8) * HID + k] = a2 * dinv[node0 + n0 + 8];
    hp1[(size_t)(node0 + n0 + 12) * HID + k] = a3 * dinv[node0 + n0 + 12];
}

// ---- layer 1 aggregate + relu + bias + layer 2 projection, fused ----
__global__ __launch_bounds__(256) void k_agg1(const int* __restrict__ rowptr,
                                              const int* __restrict__ esorted,
                                              const float* __restrict__ hp1,
                                              const float* __restrict__ dinv,
                                              const float* __restrict__ b1,
                                              const float* __restrict__ W2,
                                              float* __restrict__ hp2, int N) {
    int wid = (blockIdx.x * blockDim.x + threadIdx.x) >> 6;
    if (wid >= N) return;
    int k = threadIdx.x & 63;
    int beg = rowptr[wid], end = rowptr[wid + 1];
    float acc = hp1[(size_t)wid * HID + k];           // self-loop term
    for (int e = beg; e < end; ++e) {
        int s = esorted[e];
        acc += hp1[(size_t)s * HID + k];
    }
    float dj = dinv[wid];
    float h = fmaxf(fmaf(dj, acc, b1[k]), 0.0f);
    float p0 = h * W2[k * 2 + 0];
    float p1 = h * W2[k * 2 + 1];
#pragma unroll
    for (int off = 32; off; off >>= 1) {
        p0 += __shfl_xor(p0, off);
        p1 += __shfl_xor(p1, off);
    }
    if (k == 0) {
        hp2[(size_t)wid * 2 + 0] = p0 * dj;
        hp2[(size_t)wid * 2 + 1] = p1 * dj;
    }
}

// ---------------- layer 2 aggregate + epilogue ----------------
__global__ void k_agg2(const int* __restrict__ rowptr, const int* __restrict__ esorted,
                       const float* __restrict__ hp2, const float* __restrict__ dinv,
                       const float* __restrict__ b2, float* __restrict__ out, int N) {
    int j = blockIdx.x * blockDim.x + threadIdx.x;
    if (j >= N) return;
    int beg = rowptr[j], end = rowptr[j + 1];
    float2 a = *(const float2*)(hp2 + (size_t)j * 2);
    for (int e = beg; e < end; ++e) {
        int s = esorted[e];
        float2 v = *(const float2*)(hp2 + (size_t)s * 2);
        a.x += v.x;
        a.y += v.y;
    }
    float dj = dinv[j];
    out[(size_t)j * 2 + 0] = fmaf(dj, a.x, b2[0]);
    out[(size_t)j * 2 + 1] = fmaf(dj, a.y, b2[1]);
}

extern "C" void kernel_launch(void* const* d_in, const int* in_sizes, int n_in,
                              void* d_out, int out_size, void* d_ws, size_t ws_size,
                              hipStream_t stream) {
    const float* x  = (const float*)d_in[0];
    const int*   ei = (const int*)d_in[1];
    const float* W1 = (const float*)d_in[2];
    const float* b1 = (const float*)d_in[3];
    const float* W2 = (const float*)d_in[4];
    const float* b2 = (const float*)d_in[5];
    float* out = (float*)d_out;

    const int N = in_sizes[0] / IN_CH;   // 100000
    const int E = in_sizes[1] / 2;       // 3200000
    const int* src = ei;
    const int* dst = ei + E;
    const int NB = (N + SCAN_CHUNK - 1) / SCAN_CHUNK;  // 98 (<=128 required)

    char* ws = (char*)d_ws;
    size_t o = 0;
    auto carve = [&](size_t bytes) -> char* {
        char* p = ws + o;
        o = (o + bytes + 255) & ~(size_t)255;
        return p;
    };
    int*   cnt     = (int*)carve((size_t)N * 4);
    int*   rowptr  = (int*)carve(((size_t)N + 1) * 4);
    int*   cursor  = (int*)carve((size_t)N * 4);
    float* dinv    = (float*)carve((size_t)N * 4);
    int*   bsum    = (int*)carve(128 * 4);
    int*   esorted = (int*)carve((size_t)E * 4);          // 12.8 MB
    float* hp1     = (float*)carve((size_t)N * HID * 4);  // 25.6 MB
    float* hp2     = (float*)carve((size_t)N * 2 * 4);
    (void)ws_size;

    hipMemsetAsync(cnt, 0, (size_t)N * 4, stream);
    k_hist<<<(E + 255) / 256, 256, 0, stream>>>(dst, cnt, E);
    k_scan_blocksum<<<NB, 256, 0, stream>>>(cnt, bsum, N);
    k_scan_bsums<<<1, 128, 0, stream>>>(bsum, NB);
    k_scan_apply<<<NB, 256, 0, stream>>>(cnt, bsum, rowptr, cursor, dinv, N, E);
    k_bucket<<<4096, 256, 0, stream>>>(src, dst, cursor, esorted, E);

    k_gemm1<<<(N + 15) / 16, 256, 0, stream>>>(x, W1, dinv, hp1, N);
    k_agg1<<<(unsigned)(((size_t)N * 64 + 255) / 256), 256, 0, stream>>>(
        rowptr, esorted, hp1, dinv, b1, W2, hp2, N);
    k_agg2<<<(N + 255) / 256, 256, 0, stream>>>(rowptr, esorted, hp2, dinv, b2, out, N);
}

// Round 5
// 460.399 us; speedup vs baseline: 7.0923x; 1.3786x over previous
//
#include <hip/hip_runtime.h>

#define IN_CH 128
#define HID 64
#define SCAN_CHUNK 1024  // elements per scan block (256 threads x int4)

// ---------------- phase A: histogram of dst (= in-degree) ----------------
__global__ void k_hist(const int* __restrict__ dst, int* __restrict__ cnt, int E) {
    int e = blockIdx.x * blockDim.x + threadIdx.x;
    if (e < E) atomicAdd(&cnt[dst[e]], 1);
}

// ---------------- phase B: multi-block exclusive scan ----------------
__global__ __launch_bounds__(256) void k_scan_blocksum(const int* __restrict__ cnt,
                                                       int* __restrict__ bsum, int N) {
    int t = threadIdx.x;
    int base = blockIdx.x * SCAN_CHUNK + t * 4;
    int4 v = make_int4(0, 0, 0, 0);
    if (base + 3 < N) v = *(const int4*)(cnt + base);
    else {
        if (base     < N) v.x = cnt[base];
        if (base + 1 < N) v.y = cnt[base + 1];
        if (base + 2 < N) v.z = cnt[base + 2];
        if (base + 3 < N) v.w = cnt[base + 3];
    }
    int s = v.x + v.y + v.z + v.w;
#pragma unroll
    for (int off = 32; off; off >>= 1) s += __shfl_down(s, off);
    __shared__ int ws[4];
    if ((t & 63) == 0) ws[t >> 6] = s;
    __syncthreads();
    if (t == 0) bsum[blockIdx.x] = ws[0] + ws[1] + ws[2] + ws[3];
}

__global__ __launch_bounds__(128) void k_scan_bsums(int* __restrict__ bsum, int nb) {
    __shared__ int sh[128];
    int t = threadIdx.x;
    int v = (t < nb) ? bsum[t] : 0;
    sh[t] = v;
    __syncthreads();
    for (int off = 1; off < 128; off <<= 1) {
        int u = (t >= off) ? sh[t - off] : 0;
        __syncthreads();
        sh[t] += u;
        __syncthreads();
    }
    if (t < nb) bsum[t] = (t == 0) ? 0 : sh[t - 1];
}

__global__ __launch_bounds__(256) void k_scan_apply(const int* __restrict__ cnt,
                                                    const int* __restrict__ boff,
                                                    int* __restrict__ rowptr,
                                                    int* __restrict__ cursor,
                                                    float* __restrict__ dinv,
                                                    int N, int E) {
    int t = threadIdx.x;
    int base = blockIdx.x * SCAN_CHUNK + t * 4;
    int4 v = make_int4(0, 0, 0, 0);
    if (base + 3 < N) v = *(const int4*)(cnt + base);
    else {
        if (base     < N) v.x = cnt[base];
        if (base + 1 < N) v.y = cnt[base + 1];
        if (base + 2 < N) v.z = cnt[base + 2];
        if (base + 3 < N) v.w = cnt[base + 3];
    }
    int tsum = v.x + v.y + v.z + v.w;
    __shared__ int sh[256];
    sh[t] = tsum;
    __syncthreads();
    for (int off = 1; off < 256; off <<= 1) {
        int u = (t >= off) ? sh[t - off] : 0;
        __syncthreads();
        sh[t] += u;
        __syncthreads();
    }
    int run = ((t == 0) ? 0 : sh[t - 1]) + boff[blockIdx.x];
    int p0 = run;
    int p1 = p0 + v.x;
    int p2 = p1 + v.y;
    int p3 = p2 + v.z;
    if (base < N) {
        rowptr[base] = p0; cursor[base] = p0; dinv[base] = rsqrtf(1.0f + (float)v.x);
    }
    if (base + 1 < N) {
        rowptr[base + 1] = p1; cursor[base + 1] = p1; dinv[base + 1] = rsqrtf(1.0f + (float)v.y);
    }
    if (base + 2 < N) {
        rowptr[base + 2] = p2; cursor[base + 2] = p2; dinv[base + 2] = rsqrtf(1.0f + (float)v.z);
    }
    if (base + 3 < N) {
        rowptr[base + 3] = p3; cursor[base + 3] = p3; dinv[base + 3] = rsqrtf(1.0f + (float)v.w);
    }
    if (blockIdx.x == 0 && t == 0) rowptr[N] = E;
}

// ---------------- phase C: bucket src ids by dst, XCD-partitioned ----------------
__global__ __launch_bounds__(256) void k_bucket(const int* __restrict__ src,
                                                const int* __restrict__ dst,
                                                int* __restrict__ cursor,
                                                int* __restrict__ esorted, int E) {
    const int grp    = blockIdx.x & 7;   // heuristic XCD id (round-robin dispatch)
    const int blk    = blockIdx.x >> 3;
    const int stride = (gridDim.x >> 3) * 256;
    for (int e = blk * 256 + threadIdx.x; e < E; e += stride) {
        int d = __builtin_nontemporal_load(dst + e);
        if (((d >> 7) & 7) == grp) {
            int s = __builtin_nontemporal_load(src + e);
            int pos = atomicAdd(&cursor[d], 1);
            esorted[pos] = s;
        }
    }
}

// ---------------- layer 1 GEMM: hp1 = dinv * (x @ W1) ----------------
__global__ __launch_bounds__(256) void k_gemm1(const float* __restrict__ x,
                                               const float* __restrict__ W1,
                                               const float* __restrict__ dinv,
                                               float* __restrict__ hp1, int N) {
    __shared__ float sW[IN_CH * HID];
    __shared__ float sx[16 * IN_CH];
    const int tid = threadIdx.x;
    const int node0 = blockIdx.x * 16;

    {
        const float4* g = (const float4*)W1;
        float4* s = (float4*)sW;
        for (int i = tid; i < IN_CH * HID / 4; i += 256) s[i] = g[i];
    }
    {
        const float4* g = (const float4*)(x + (size_t)node0 * IN_CH);
        float4* s = (float4*)sx;
        for (int i = tid; i < 16 * IN_CH / 4; i += 256) s[i] = g[i];
    }
    __syncthreads();

    const int k  = tid & 63;
    const int n0 = tid >> 6;  // 0..3
    float a0 = 0.f, a1 = 0.f, a2 = 0.f, a3 = 0.f;
#pragma unroll 8
    for (int j = 0; j < IN_CH; ++j) {
        float w = sW[j * HID + k];
        a0 = fmaf(sx[(n0     ) * IN_CH + j], w, a0);
        a1 = fmaf(sx[(n0 +  4) * IN_CH + j], w, a1);
        a2 = fmaf(sx[(n0 +  8) * IN_CH + j], w, a2);
        a3 = fmaf(sx[(n0 + 12) * IN_CH + j], w, a3);
    }
    hp1[(size_t)(node0 + n0     ) * HID + k] = a0 * dinv[node0 + n0];
    hp1[(size_t)(node0 + n0 +  4) * HID + k] = a1 * dinv[node0 + n0 + 4];
    hp1[(size_t)(node0 + n0 +  8) * HID + k] = a2 * dinv[node0 + n0 + 8];
    hp1[(size_t)(node0 + n0 + 12) * HID + k] = a3 * dinv[node0 + n0 + 12];
}

// ---- layer 1 aggregate + relu + bias + layer 2 projection, fused ----
// One wave per node, lane k = dim k. Edge loop unrolled x8 with independent
// accumulators: 8 row-gathers in flight per wave breaks the load-use chain
// (latency-bound at 1-deep: 275us, FETCH 1.35 TB/s, VALUBusy 16%).
__global__ __launch_bounds__(256) void k_agg1(const int* __restrict__ rowptr,
                                              const int* __restrict__ esorted,
                                              const float* __restrict__ hp1,
                                              const float* __restrict__ dinv,
                                              const float* __restrict__ b1,
                                              const float* __restrict__ W2,
                                              float* __restrict__ hp2, int N) {
    int wid = (blockIdx.x * blockDim.x + threadIdx.x) >> 6;
    if (wid >= N) return;
    int k = threadIdx.x & 63;
    int beg = rowptr[wid], end = rowptr[wid + 1];
    float a0 = hp1[(size_t)wid * HID + k];  // self-loop term
    float a1 = 0.f, a2 = 0.f, a3 = 0.f, a4 = 0.f, a5 = 0.f, a6 = 0.f, a7 = 0.f;
    int e = beg;
    for (; e + 7 < end; e += 8) {
        int s0 = esorted[e + 0], s1 = esorted[e + 1];
        int s2 = esorted[e + 2], s3 = esorted[e + 3];
        int s4 = esorted[e + 4], s5 = esorted[e + 5];
        int s6 = esorted[e + 6], s7 = esorted[e + 7];
        a0 += hp1[(size_t)s0 * HID + k];
        a1 += hp1[(size_t)s1 * HID + k];
        a2 += hp1[(size_t)s2 * HID + k];
        a3 += hp1[(size_t)s3 * HID + k];
        a4 += hp1[(size_t)s4 * HID + k];
        a5 += hp1[(size_t)s5 * HID + k];
        a6 += hp1[(size_t)s6 * HID + k];
        a7 += hp1[(size_t)s7 * HID + k];
    }
    for (; e < end; ++e) a0 += hp1[(size_t)esorted[e] * HID + k];
    float acc = ((a0 + a1) + (a2 + a3)) + ((a4 + a5) + (a6 + a7));

    float dj = dinv[wid];
    float h = fmaxf(fmaf(dj, acc, b1[k]), 0.0f);
    float p0 = h * W2[k * 2 + 0];
    float p1 = h * W2[k * 2 + 1];
#pragma unroll
    for (int off = 32; off; off >>= 1) {
        p0 += __shfl_xor(p0, off);
        p1 += __shfl_xor(p1, off);
    }
    if (k == 0) {
        hp2[(size_t)wid * 2 + 0] = p0 * dj;
        hp2[(size_t)wid * 2 + 1] = p1 * dj;
    }
}

// ---------------- layer 2 aggregate + epilogue ----------------
// 8 lanes per node (aligned group), strided edges, shfl_xor reduce.
__global__ __launch_bounds__(256) void k_agg2(const int* __restrict__ rowptr,
                                              const int* __restrict__ esorted,
                                              const float* __restrict__ hp2,
                                              const float* __restrict__ dinv,
                                              const float* __restrict__ b2,
                                              float* __restrict__ out, int N) {
    int gid = blockIdx.x * blockDim.x + threadIdx.x;
    int j = gid >> 3;
    if (j >= N) return;
    int l = gid & 7;
    int beg = rowptr[j], end = rowptr[j + 1];
    float ax = 0.f, ay = 0.f;
    for (int e = beg + l; e < end; e += 8) {
        int s = esorted[e];
        float2 v = *(const float2*)(hp2 + (size_t)s * 2);
        ax += v.x;
        ay += v.y;
    }
#pragma unroll
    for (int off = 1; off < 8; off <<= 1) {
        ax += __shfl_xor(ax, off);
        ay += __shfl_xor(ay, off);
    }
    if (l == 0) {
        float2 self = *(const float2*)(hp2 + (size_t)j * 2);
        float dj = dinv[j];
        out[(size_t)j * 2 + 0] = fmaf(dj, ax + self.x, b2[0]);
        out[(size_t)j * 2 + 1] = fmaf(dj, ay + self.y, b2[1]);
    }
}

extern "C" void kernel_launch(void* const* d_in, const int* in_sizes, int n_in,
                              void* d_out, int out_size, void* d_ws, size_t ws_size,
                              hipStream_t stream) {
    const float* x  = (const float*)d_in[0];
    const int*   ei = (const int*)d_in[1];
    const float* W1 = (const float*)d_in[2];
    const float* b1 = (const float*)d_in[3];
    const float* W2 = (const float*)d_in[4];
    const float* b2 = (const float*)d_in[5];
    float* out = (float*)d_out;

    const int N = in_sizes[0] / IN_CH;   // 100000
    const int E = in_sizes[1] / 2;       // 3200000
    const int* src = ei;
    const int* dst = ei + E;
    const int NB = (N + SCAN_CHUNK - 1) / SCAN_CHUNK;  // 98 (<=128 required)

    char* ws = (char*)d_ws;
    size_t o = 0;
    auto carve = [&](size_t bytes) -> char* {
        char* p = ws + o;
        o = (o + bytes + 255) & ~(size_t)255;
        return p;
    };
    int*   cnt     = (int*)carve((size_t)N * 4);
    int*   rowptr  = (int*)carve(((size_t)N + 1) * 4);
    int*   cursor  = (int*)carve((size_t)N * 4);
    float* dinv    = (float*)carve((size_t)N * 4);
    int*   bsum    = (int*)carve(128 * 4);
    int*   esorted = (int*)carve((size_t)E * 4);          // 12.8 MB
    float* hp1     = (float*)carve((size_t)N * HID * 4);  // 25.6 MB
    float* hp2     = (float*)carve((size_t)N * 2 * 4);
    (void)ws_size;

    hipMemsetAsync(cnt, 0, (size_t)N * 4, stream);
    k_hist<<<(E + 255) / 256, 256, 0, stream>>>(dst, cnt, E);
    k_scan_blocksum<<<NB, 256, 0, stream>>>(cnt, bsum, N);
    k_scan_bsums<<<1, 128, 0, stream>>>(bsum, NB);
    k_scan_apply<<<NB, 256, 0, stream>>>(cnt, bsum, rowptr, cursor, dinv, N, E);
    k_bucket<<<4096, 256, 0, stream>>>(src, dst, cursor, esorted, E);

    k_gemm1<<<(N + 15) / 16, 256, 0, stream>>>(x, W1, dinv, hp1, N);
    k_agg1<<<(unsigned)(((size_t)N * 64 + 255) / 256), 256, 0, stream>>>(
        rowptr, esorted, hp1, dinv, b1, W2, hp2, N);
    k_agg2<<<(unsigned)(((size_t)N * 8 + 255) / 256), 256, 0, stream>>>(
        rowptr, esorted, hp2, dinv, b2, out, N);
}